// Round 3
// baseline (697.719 us; speedup 1.0000x reference)
//
#include <hip/hip_runtime.h>
#include <hip/hip_bf16.h>
#include <stdint.h>

// Problem constants (JinaEmbeddingsV3SelfOutput): B=16, S=2048, D=1024, rank=4.
// ALL float tensors are fp32 (per reference setup_inputs); adapter_mask int32.
// Output fp32. MFMA path: convert fp32->bf16 during LDS staging, fp32 accum.
#define D_HID 1024
#define M_TOT 32768            // 16*2048 rows
#define LORA_SCALE 0.25f       // 1/rank
#define LN_EPS 1e-5f

typedef __bf16 bf16x8 __attribute__((ext_vector_type(8)));
typedef float f32x4 __attribute__((ext_vector_type(4)));
typedef unsigned short u16;
typedef u16 u16x8 __attribute__((ext_vector_type(8)));

__device__ __forceinline__ float bf2f(u16 x) {
  union { unsigned int u; float f; } c; c.u = ((unsigned int)x) << 16; return c.f;
}
__device__ __forceinline__ u16 f2bf(float f) {
  union { __bf16 h; u16 u; } c; c.h = (__bf16)f;  // compiler RNE cvt
  return c.u;
}
// Load 8 consecutive fp32, convert to 8 bf16.
__device__ __forceinline__ u16x8 cvt8(const float* g) {
  float4 f0 = *(const float4*)g;
  float4 f1 = *(const float4*)(g + 4);
  u16x8 v;
  v[0] = f2bf(f0.x); v[1] = f2bf(f0.y); v[2] = f2bf(f0.z); v[3] = f2bf(f0.w);
  v[4] = f2bf(f1.x); v[5] = f2bf(f1.y); v[6] = f2bf(f1.z); v[7] = f2bf(f1.w);
  return v;
}

// C = A[M,K] @ Bt[N,K]^T + bias. A is fp32 (A_BF16=false) or bf16 (true).
// Bt fp32 (converted while staging). fp32 accum.
// !FUSED: writes bf16 to Cbf (h1).  FUSED: adds LORA_SCALE*(low.loraB^T)+resid,
// writes fp32 to Cf (pre-LN).
// 128x128 tile, BK=32, 4 waves (2x2 of 64x64), 16x16x32 bf16 MFMA, sync staging.
template <bool FUSED, bool A_BF16>
__global__ __launch_bounds__(256, 2)
void gemm_bt(const void* Aptr, const float* __restrict__ Bt,
             const float* __restrict__ bias,
             u16* __restrict__ Cbf, float* __restrict__ Cf,
             const float* __restrict__ low, const float* __restrict__ loraB,
             const float* __restrict__ resid, const int* __restrict__ mask) {
  const float* Af = (const float*)Aptr;
  const u16*   Ab = (const u16*)Aptr;

  __shared__ __align__(16) u16 sA[128 * 32];
  __shared__ __align__(16) u16 sB[128 * 32];

  const int tid  = threadIdx.x;
  const int wave = tid >> 6;
  const int lane = tid & 63;
  const int bx = blockIdx.x;   // N tile (0..7)
  const int by = blockIdx.y;   // M tile (0..255)

  // staging: thread t covers rows (t>>2), (t>>2)+64; k-chunk (t&3)*8 (8 elems).
  const int srow = tid >> 2;
  const int scol = (tid & 3) * 8;
  size_t aOff = (size_t)(by * 128 + srow) * D_HID + scol;
  size_t bOff = (size_t)(bx * 128 + srow) * D_HID + scol;
  u16* wA = sA + srow * 32 + scol;
  u16* wB = sB + srow * 32 + scol;

  // fragment addressing (A-op: m=lane&15, k=quad*8+j; B-op same with n)
  const int wm = wave >> 1, wn = wave & 1;
  const int mrow = lane & 15;
  const int quad = lane >> 4;
  const u16* pA = sA + (wm * 64 + mrow) * 32 + quad * 8;
  const u16* pB = sB + (wn * 64 + mrow) * 32 + quad * 8;

  f32x4 acc[4][4];
#pragma unroll
  for (int i = 0; i < 4; ++i)
#pragma unroll
    for (int j = 0; j < 4; ++j) acc[i][j] = (f32x4){0.f, 0.f, 0.f, 0.f};

  for (int k0 = 0; k0 < D_HID; k0 += 32) {
    u16x8 a0, a1, b0, b1;
    if constexpr (A_BF16) {
      a0 = *(const u16x8*)(Ab + aOff);
      a1 = *(const u16x8*)(Ab + aOff + (size_t)64 * D_HID);
    } else {
      a0 = cvt8(Af + aOff);
      a1 = cvt8(Af + aOff + (size_t)64 * D_HID);
    }
    b0 = cvt8(Bt + bOff);
    b1 = cvt8(Bt + bOff + (size_t)64 * D_HID);
    aOff += 32; bOff += 32;

    __syncthreads();  // prior iteration's LDS reads done
    *(u16x8*)wA             = a0;
    *(u16x8*)(wA + 64 * 32) = a1;
    *(u16x8*)wB             = b0;
    *(u16x8*)(wB + 64 * 32) = b1;
    __syncthreads();  // tile visible

    bf16x8 af[4], bfr[4];
#pragma unroll
    for (int mf = 0; mf < 4; ++mf) af[mf]  = *(const bf16x8*)(pA + mf * 16 * 32);
#pragma unroll
    for (int nf = 0; nf < 4; ++nf) bfr[nf] = *(const bf16x8*)(pB + nf * 16 * 32);
#pragma unroll
    for (int mf = 0; mf < 4; ++mf)
#pragma unroll
      for (int nf = 0; nf < 4; ++nf)
        acc[mf][nf] = __builtin_amdgcn_mfma_f32_16x16x32_bf16(
            af[mf], bfr[nf], acc[mf][nf], 0, 0, 0);
  }

  // epilogue. C/D layout: col = lane&15, row = quad*4 + reg (verified m89).
  const size_t mBase = (size_t)by * 128 + wm * 64;
  const int nBase = bx * 128 + wn * 64;
  int task = 0;
  if (FUSED) task = mask[(by * 128) >> 11];  // 128-row tile never crosses batch
  const float* lbBase = FUSED ? (loraB + (size_t)task * 4096) : nullptr;

#pragma unroll
  for (int mf = 0; mf < 4; ++mf) {
    f32x4 lowv[4];
    if (FUSED) {
#pragma unroll
      for (int r = 0; r < 4; ++r) {
        size_t m = mBase + mf * 16 + quad * 4 + r;
        lowv[r] = *(const f32x4*)(low + m * 4);
      }
    }
#pragma unroll
    for (int nf = 0; nf < 4; ++nf) {
      const int n = nBase + nf * 16 + mrow;
      const float bval = bias[n];
      float4 lb = {0.f, 0.f, 0.f, 0.f};
      if (FUSED) lb = *(const float4*)(lbBase + n * 4);
#pragma unroll
      for (int r = 0; r < 4; ++r) {
        const size_t m = mBase + mf * 16 + quad * 4 + r;
        float v = acc[mf][nf][r] + bval;
        if (FUSED) {
          float d = lowv[r].x * lb.x + lowv[r].y * lb.y +
                    lowv[r].z * lb.z + lowv[r].w * lb.w;
          v += LORA_SCALE * d + resid[m * D_HID + n];
          Cf[m * D_HID + n] = v;
        } else {
          Cbf[m * D_HID + n] = f2bf(v);
        }
      }
    }
  }
}

// low[m,r] = sum_d h1[m,d] * loraA[task(m), r, d].  h1 bf16, loraA fp32.
// One wave per row.
__global__ __launch_bounds__(256)
void lora_low(const u16* __restrict__ h1, const float* __restrict__ loraA,
              const int* __restrict__ mask, float* __restrict__ low) {
  const int row  = blockIdx.x * 4 + (threadIdx.x >> 6);
  const int lane = threadIdx.x & 63;
  const int task = mask[row >> 11];
  const u16* hp = h1 + (size_t)row * D_HID + lane * 16;
  const float* ap = loraA + (size_t)task * 4096 + lane * 16;
  u16x8 h0 = *(const u16x8*)hp;
  u16x8 h1v = *(const u16x8*)(hp + 8);
  float hv[16];
#pragma unroll
  for (int j = 0; j < 8; ++j) { hv[j] = bf2f(h0[j]); hv[8 + j] = bf2f(h1v[j]); }
  float acc[4];
#pragma unroll
  for (int r = 0; r < 4; ++r) {
    const float* a = ap + r * D_HID;
    float4 a0 = *(const float4*)a;
    float4 a1 = *(const float4*)(a + 4);
    float4 a2 = *(const float4*)(a + 8);
    float4 a3 = *(const float4*)(a + 12);
    acc[r] = hv[0]*a0.x + hv[1]*a0.y + hv[2]*a0.z + hv[3]*a0.w
           + hv[4]*a1.x + hv[5]*a1.y + hv[6]*a1.z + hv[7]*a1.w
           + hv[8]*a2.x + hv[9]*a2.y + hv[10]*a2.z + hv[11]*a2.w
           + hv[12]*a3.x + hv[13]*a3.y + hv[14]*a3.z + hv[15]*a3.w;
  }
#pragma unroll
  for (int off = 32; off > 0; off >>= 1)
#pragma unroll
    for (int r = 0; r < 4; ++r) acc[r] += __shfl_down(acc[r], off);
  if (lane == 0) {
    f32x4 v = {acc[0], acc[1], acc[2], acc[3]};
    *(f32x4*)(low + (size_t)row * 4) = v;
  }
}

// In-place row LayerNorm on fp32 d_out. One 256-thread block per row.
__global__ __launch_bounds__(256)
void ln_kernel(float* __restrict__ io, const float* __restrict__ gamma,
               const float* __restrict__ beta) {
  const int row = blockIdx.x;
  const int tid = threadIdx.x;
  float* p = io + (size_t)row * D_HID + tid * 4;
  float4 v = *(const float4*)p;
  float s = v.x + v.y + v.z + v.w;
  float q = v.x * v.x + v.y * v.y + v.z * v.z + v.w * v.w;
#pragma unroll
  for (int off = 32; off > 0; off >>= 1) {
    s += __shfl_down(s, off);
    q += __shfl_down(q, off);
  }
  __shared__ float red[8];
  const int wave = tid >> 6, lane = tid & 63;
  if (lane == 0) { red[wave] = s; red[4 + wave] = q; }
  __syncthreads();
  const float tot  = red[0] + red[1] + red[2] + red[3];
  const float totq = red[4] + red[5] + red[6] + red[7];
  const float mu  = tot * (1.f / (float)D_HID);
  const float var = totq * (1.f / (float)D_HID) - mu * mu;
  const float inv = rsqrtf(var + LN_EPS);
  float4 g  = *(const float4*)(gamma + tid * 4);
  float4 bb = *(const float4*)(beta  + tid * 4);
  float4 o;
  o.x = (v.x - mu) * inv * g.x + bb.x;
  o.y = (v.y - mu) * inv * g.y + bb.y;
  o.z = (v.z - mu) * inv * g.z + bb.z;
  o.w = (v.w - mu) * inv * g.w + bb.w;
  *(float4*)p = o;
}

extern "C" void kernel_launch(void* const* d_in, const int* in_sizes, int n_in,
                              void* d_out, int out_size, void* d_ws, size_t ws_size,
                              hipStream_t stream) {
  const float* hs    = (const float*)d_in[0];  // [16,2048,1024] fp32
  const float* inp   = (const float*)d_in[1];  // [16,2048,1024] fp32
  const float* W     = (const float*)d_in[2];  // [1024,1024] fp32 (row e, col d = B^T)
  const float* b     = (const float*)d_in[3];  // [1024] fp32
  const float* lA    = (const float*)d_in[4];  // [5,4,1024] fp32
  const float* lB    = (const float*)d_in[5];  // [5,1024,4] fp32
  const float* gamma = (const float*)d_in[6];  // [1024] fp32
  const float* beta  = (const float*)d_in[7];  // [1024] fp32
  const int*   mask  = (const int*)d_in[8];    // [16] int32
  float* out = (float*)d_out;                  // [16,2048,1024] fp32

  // Workspace: h1 (bf16, 64 MB) + low (fp32, 512 KB). Pre-LN is fp32 in d_out.
  u16*   h1  = (u16*)d_ws;
  float* low = (float*)((char*)d_ws + (size_t)M_TOT * D_HID * sizeof(u16));

  dim3 grid(D_HID / 128, M_TOT / 128);  // (8, 256)
  gemm_bt<false, false><<<grid, 256, 0, stream>>>(
      hs, W, b, h1, nullptr, nullptr, nullptr, nullptr, mask);
  lora_low<<<M_TOT / 4, 256, 0, stream>>>(h1, lA, mask, low);
  gemm_bt<true, true><<<grid, 256, 0, stream>>>(
      h1, W, b, nullptr, out, low, lB, inp, mask);
  ln_kernel<<<M_TOT, 256, 0, stream>>>(out, gamma, beta);
}